// Round 4
// baseline (224.281 us; speedup 1.0000x reference)
//
#include <hip/hip_runtime.h>
#include <stdint.h>

// MHA forward, B=8 T=1024 C=1024 H=16 D=64.
// cast3 -> QKV GEMM (256x128 tile, 3-slot rotation 8-phase-style counted-vmcnt,
// LDS 72 KiB -> 2 blocks/CU for cross-block stall hiding; 768 blocks = 3/CU;
// writes packed QK [stride 2048, Q pre-scaled] + V^T)
// -> flash attention (512-thr blocks, 128-row q-tile pairs, peeled causal mask,
// deferred l-reduction) -> proj GEMM (same body, 256 blocks, fp32 +bias).
// 4 launches. Kernel names split for per-stage profiling.

#define Bn 8
#define Tn 1024
#define Cn 1024
#define Hn 16
#define Dn 64
#define Mn (Bn * Tn)      // 8192
#define NQKV (3 * Cn)     // 3072
#define QKS 2048          // packed QK row stride

typedef unsigned short u16;
typedef float f32x4 __attribute__((ext_vector_type(4)));
typedef __bf16 bf16x8 __attribute__((ext_vector_type(8)));
typedef unsigned short ushx8 __attribute__((ext_vector_type(8)));
typedef unsigned short ushx4 __attribute__((ext_vector_type(4)));

__device__ __forceinline__ u16 f2bf(float f) {
  unsigned int u = __float_as_uint(f);
  u += 0x7fffu + ((u >> 16) & 1u);   // RTN-even
  return (u16)(u >> 16);
}
__device__ __forceinline__ u16 f2bf_rna(float f) {
  return (u16)((__float_as_uint(f) + 0x8000u) >> 16);
}

__device__ __forceinline__ f32x4 mfma_bf16(ushx8 a, ushx8 b, f32x4 c) {
  return __builtin_amdgcn_mfma_f32_16x16x32_bf16(
      __builtin_bit_cast(bf16x8, a), __builtin_bit_cast(bf16x8, b), c, 0, 0, 0);
}

// async global->LDS, 16B per lane; LDS dest = wave-uniform base + lane*16 (m104)
__device__ __forceinline__ void async16(const u16* g, u16* l) {
  __builtin_amdgcn_global_load_lds(
      (__attribute__((address_space(1))) void*)(void*)g,
      (__attribute__((address_space(3))) void*)l, 16, 0, 0);
}

// ---- DPP 16-lane butterfly reductions (VALU-rate, no LDS pipe) ----
template <int CTRL>
__device__ __forceinline__ float dppmov(float v) {
  return __builtin_bit_cast(float, __builtin_amdgcn_update_dpp(
      0, __builtin_bit_cast(int, v), CTRL, 0xf, 0xf, true));
}
__device__ __forceinline__ float red16max(float v) {
  v = fmaxf(v, dppmov<0xB1>(v));
  v = fmaxf(v, dppmov<0x4E>(v));
  v = fmaxf(v, dppmov<0x141>(v));
  v = fmaxf(v, dppmov<0x140>(v));
  return v;
}
__device__ __forceinline__ float red16sum(float v) {
  v += dppmov<0xB1>(v);
  v += dppmov<0x4E>(v);
  v += dppmov<0x141>(v);
  v += dppmov<0x140>(v);
  return v;
}

// ---------------- fused cast fp32 -> bf16 (3 tensors, 1 launch) ----------------
__global__ void cast3_kernel(const float* __restrict__ a, u16* __restrict__ oa, int na4,
                             const float* __restrict__ b, u16* __restrict__ ob, int nb4,
                             const float* __restrict__ c, u16* __restrict__ oc, int nc4) {
  int i = blockIdx.x * blockDim.x + threadIdx.x;
  const float* in;
  u16* out;
  if (i < na4) { in = a; out = oa; }
  else if (i < na4 + nb4) { in = b; out = ob; i -= na4; }
  else if (i < na4 + nb4 + nc4) { in = c; out = oc; i -= na4 + nb4; }
  else return;
  float4 v = ((const float4*)in)[i];
  ushx4 o = { f2bf(v.x), f2bf(v.y), f2bf(v.z), f2bf(v.w) };
  ((ushx4*)out)[i] = o;
}

#define SLOG2E 0.18033688011112042f

// ---------------- GEMM body: 256x128 tile, BK=64, 3-slot rotating pipeline ----------
// 512 threads = 8 waves (4 M x 2 N); per-wave 64x64 output = acc[4][4].
// LDS 72 KiB: A = 3 slots x [256][32] (8192 u16) at 0; B = 3 slots x [128][32]
// (4096 u16) at +24576 u16. Chunk swizzle p = q ^ ((row>>1)&3), conflict-free.
// 2 blocks/CU (144 KiB) -> two independent barrier groups: one block's
// read-drain/vmcnt stalls overlap the other's MFMA.
//
// Half-tiles h = 0..31 (K-tile h>>1, kk h&1); slot(h) = h % 3.
// Phase p: read slot p%3 (h=p); stage h'=min(p+2,31) into slot (p+2)%3
// (= slot read at p-1; readers crossed the p-1 closing barrier before this
// stage issues); barrier; lgkmcnt(0); 16 MFMA; vmcnt(3); barrier.
// vmcnt(3) at end-p drains phase p-1's 3 loads -> phase p+1's data confirmed
// with a 1-phase issue->confirm gap (~1300cy solo > 900cy HBM).
// Prologue: stage h0->slot0, h1->slot1 (6 loads); vmcnt(3) confirms h0.
// Tail: stages clamp DATA to h=31; targets are slots whose readers are done.
// MODE=1: cols [0,2048)->packed QK (Q pre-scaled); [2048,3072)->V^T.
// MODE=0: fp32 out + bias (N = Cn).
template <int MODE>
__device__ __forceinline__ void gemm_body(
    const u16* __restrict__ A, const u16* __restrict__ Bw,
    void* __restrict__ Cout, u16* __restrict__ vt,
    const float* __restrict__ bias) {
  __shared__ alignas(16) u16 lds[36864];  // 72 KiB

  const int tid = threadIdx.x;
  const int lane = tid & 63;
  const int wv = tid >> 6;       // 0..7
  const int quad = lane >> 4;
  const int l16 = lane & 15;
  const int wr = wv >> 1;        // 0..3 (M)
  const int wc = wv & 1;         // 0..1 (N)

  // XCD chunk map: xcd = bid&7 owns 4 consecutive 256-row m-tiles x all
  // n-tiles, m-fastest (A chunk 2 MiB fits XCD L2; B panel reused 4x).
  const int xcd = blockIdx.x & 7;
  const int loc = blockIdx.x >> 3;
  const int m0 = (xcd * 4 + (loc & 3)) * 256;
  const int n0 = (loc >> 2) * 128;

  const u16* gA = A + (size_t)m0 * Cn;
  const u16* gB = Bw + (size_t)n0 * Cn;

  // staging source offsets: chunk c -> row c>>2, stored chunk c&3,
  // global k-chunk q = (c&3) ^ ((row>>1)&3)  (XOR is its own inverse)
  const int r0s = tid >> 2;
  const int q0s = (tid & 3) ^ ((r0s >> 1) & 3);
  const int c1s = 512 + tid;
  const int r1s = c1s >> 2;
  const int q1s = (c1s & 3) ^ ((r1s >> 1) & 3);
  const int so0 = r0s * Cn + q0s * 8;
  const int so1 = r1s * Cn + q1s * 8;

  auto stageA = [&](int slot, int h) {
    u16* dst = lds + slot * 8192 + tid * 8;
    const u16* src = gA + (h >> 1) * 64 + (h & 1) * 32;
    async16(src + so0, dst);
    async16(src + so1, dst + 4096);
  };
  auto stageB = [&](int slot, int h) {
    u16* dst = lds + 24576 + slot * 4096 + tid * 8;
    const u16* src = gB + (h >> 1) * 64 + (h & 1) * 32;
    async16(src + so0, dst);
  };

  // fragment read offsets (u16, within one half-region)
  const int sread = (quad ^ ((l16 >> 1) & 3)) * 8;
  const int aoff = (wr * 64 + l16) * 32 + sread;            // + mi*512 + slot*8192
  const int boff = 24576 + (wc * 64 + l16) * 32 + sread;    // + ni*512 + slot*4096

  f32x4 acc[4][4];
#pragma unroll
  for (int i = 0; i < 4; ++i)
#pragma unroll
    for (int j = 0; j < 4; ++j) acc[i][j] = (f32x4){0.f, 0.f, 0.f, 0.f};
  ushx8 af[4], bfr[4];

  // prologue: h0->slot0, h1->slot1 (6 loads); vmcnt(3) confirms h0
  stageA(0, 0); stageB(0, 0);
  stageA(1, 1); stageB(1, 1);
  asm volatile("s_waitcnt vmcnt(3)" ::: "memory");
  __builtin_amdgcn_s_barrier();
  asm volatile("" ::: "memory");

#define PH(slot, sslot, hd)                                                    \
  {                                                                            \
    const u16* ab_ = lds + (slot) * 8192 + aoff;                               \
    af[0] = *(const ushx8*)(ab_);                                              \
    af[1] = *(const ushx8*)(ab_ + 512);                                        \
    af[2] = *(const ushx8*)(ab_ + 1024);                                       \
    af[3] = *(const ushx8*)(ab_ + 1536);                                       \
    const u16* bb_ = lds + (slot) * 4096 + boff;                               \
    bfr[0] = *(const ushx8*)(bb_);                                             \
    bfr[1] = *(const ushx8*)(bb_ + 512);                                       \
    bfr[2] = *(const ushx8*)(bb_ + 1024);                                      \
    bfr[3] = *(const ushx8*)(bb_ + 1536);                                      \
    stageA((sslot), (hd));                                                     \
    stageB((sslot), (hd));                                                     \
    asm volatile("" ::: "memory");                                             \
    __builtin_amdgcn_s_barrier();                                              \
    asm volatile("s_waitcnt lgkmcnt(0)" ::: "memory");                         \
    __builtin_amdgcn_s_setprio(1);                                             \
    _Pragma("unroll") for (int mi_ = 0; mi_ < 4; ++mi_) {                      \
      _Pragma("unroll") for (int ni_ = 0; ni_ < 4; ++ni_) {                    \
        acc[mi_][ni_] = mfma_bf16(af[mi_], bfr[ni_], acc[mi_][ni_]);           \
      }                                                                        \
    }                                                                          \
    __builtin_amdgcn_s_setprio(0);                                             \
    asm volatile("s_waitcnt vmcnt(3)" ::: "memory");                           \
    asm volatile("" ::: "memory");                                             \
    __builtin_amdgcn_s_barrier();                                              \
    asm volatile("" ::: "memory");                                             \
  }

  // phases 0..29: five groups of 6 (slot pattern 0,1,2,0,1,2)
#pragma unroll 1
  for (int it = 0; it < 5; ++it) {
    const int p = it * 6;
    PH(0, 2, p + 2)
    PH(1, 0, p + 3)
    PH(2, 1, p + 4)
    PH(0, 2, p + 5)
    PH(1, 0, p + 6)
    PH(2, 1, p + 7)
  }
  // tail: phases 30, 31 (stages clamp to h=31; targets never read again)
  PH(0, 2, 31)
  PH(1, 0, 31)
#undef PH
  asm volatile("s_waitcnt vmcnt(0)" ::: "memory");

  // epilogue
  if constexpr (MODE) {
    if (n0 < 2 * Cn) {
      const float sc = (n0 < Cn) ? SLOG2E : 1.f;
#pragma unroll
      for (int mi = 0; mi < 4; ++mi) {
#pragma unroll
        for (int ni = 0; ni < 4; ++ni) {
          const int col = n0 + wc * 64 + ni * 16 + l16;
          const int row = m0 + wr * 64 + mi * 16 + quad * 4;
#pragma unroll
          for (int i = 0; i < 4; ++i)
            ((u16*)Cout)[(size_t)(row + i) * QKS + col] = f2bf(acc[mi][ni][i] * sc);
        }
      }
    } else {
#pragma unroll
      for (int mi = 0; mi < 4; ++mi) {
#pragma unroll
        for (int ni = 0; ni < 4; ++ni) {
          const int colV = n0 - 2 * Cn + wc * 64 + ni * 16 + l16;  // 0..1023
          const int hh = colV >> 6, dd = colV & 63;
          const int row0 = m0 + wr * 64 + mi * 16 + quad * 4;
          const int bb = row0 >> 10, tt = row0 & 1023;
          unsigned int lo = (unsigned int)f2bf(acc[mi][ni][0]) |
                            ((unsigned int)f2bf(acc[mi][ni][1]) << 16);
          unsigned int hi = (unsigned int)f2bf(acc[mi][ni][2]) |
                            ((unsigned int)f2bf(acc[mi][ni][3]) << 16);
          uint2 pk = {lo, hi};
          *(uint2*)&vt[((size_t)(bb * Hn + hh) * Dn + dd) * Tn + tt] = pk;
        }
      }
    }
  } else {
#pragma unroll
    for (int mi = 0; mi < 4; ++mi) {
#pragma unroll
      for (int ni = 0; ni < 4; ++ni) {
        const int col = n0 + wc * 64 + ni * 16 + l16;
        const float bv = bias[col];
        const int row = m0 + wr * 64 + mi * 16 + quad * 4;
#pragma unroll
        for (int i = 0; i < 4; ++i)
          ((float*)Cout)[(size_t)(row + i) * Cn + col] = acc[mi][ni][i] + bv;
      }
    }
  }
}

// named wrappers so rocprof separates the two GEMMs
__global__ __launch_bounds__(512, 4) void gemm_qkv_k(
    const u16* __restrict__ A, const u16* __restrict__ Bw,
    u16* __restrict__ qk, u16* __restrict__ vt) {
  gemm_body<1>(A, Bw, (void*)qk, vt, nullptr);
}
__global__ __launch_bounds__(512, 4) void gemm_proj_k(
    const u16* __restrict__ A, const u16* __restrict__ Bw,
    float* __restrict__ out, const float* __restrict__ bias) {
  gemm_body<0>(A, Bw, (void*)out, nullptr, bias);
}

// ---------------- flash attention v5 ----------------
// 512 blocks (4,16,8) x 512 threads (8 waves). Block j does 128-row q-tiles
// j and 7-j (18 kv-tiles total — balanced, 2 blocks/CU = 16 waves/CU).
// Wave wv owns q rows [wv*16, wv*16+16). Per wave one diagonal kv-tile.
// Double-buffered async K/V^T staging; DPP reductions; raw v_exp_f32;
// per-lane l partials reduced once per phase. QK stride 2048, Q pre-scaled.
__global__ __launch_bounds__(512, 4) void attn_kernel(
    const u16* __restrict__ qk, const u16* __restrict__ vt,
    u16* __restrict__ out) {
  const int j = blockIdx.x, h = blockIdx.y, b = blockIdx.z;
  const int tid = threadIdx.x;
  const int lane = tid & 63;
  const int wv = tid >> 6;           // 0..7
  const int quad = lane >> 4;
  const int l16 = lane & 15;

  __shared__ alignas(16) u16 Ks[2][64 * 64];   // [buf][kv][d] XOR-swizzled
  __shared__ alignas(16) u16 Vts[2][64 * 64];  // [buf][d][kv] XOR-swizzled
  __shared__ alignas(16) u16 Ps[8][16 * 72];   // per-wave P

  const u16* qb = qk + (size_t)b * Tn * QKS + h * Dn;
  const u16* kb = qk + (size_t)b * Tn * QKS + Cn + h * Dn;
  const u16* vtb = vt + (size_t)(b * Hn + h) * Dn * Tn;

  const int srow = tid >> 3;  // 0..63
  const int scc = tid & 7;
  const int sgc = scc ^ (srow & 7);
  u16* pswv = Ps[wv];

#pragma unroll 1
  for (int ph = 0; ph < 2; ++ph) {
    const int qt = ph ? (7 - j) : j;
    const int q0w = qt * 128 + wv * 16;   // this wave's first q row
    const int ntiles = 2 * qt + 2;
    const int tdiag = q0w >> 6;           // in-phase diagonal tile index

    // Q fragments (A-operand: m=l16, k=quad*8+jj); already scaled by SLOG2E
    ushx8 qf[2];
    {
      const u16* qp = qb + (size_t)(q0w + l16) * QKS + quad * 8;
      qf[0] = *(const ushx8*)qp;
      qf[1] = *(const ushx8*)(qp + 32);
    }

    f32x4 o[4];
#pragma unroll
    for (int nt = 0; nt < 4; ++nt) o[nt] = (f32x4){0.f, 0.f, 0.f, 0.f};
    float mrow[4], lrow[4];
#pragma unroll
    for (int i = 0; i < 4; ++i) { mrow[i] = -__builtin_inff(); lrow[i] = 0.f; }

    __syncthreads();  // previous phase's compute done before overwriting buf0

    // prefetch tile 0 -> buf 0 (one 16B DMA per thread per buffer)
    async16(kb + (size_t)srow * QKS + sgc * 8, Ks[0] + tid * 8);
    async16(vtb + (size_t)srow * Tn + sgc * 8, Vts[0] + tid * 8);

#pragma unroll 1
    for (int t = 0; t < ntiles; ++t) {
      const int kv0 = t * 64;
      const int bi = t & 1;
      __syncthreads();  // drains DMA for buf[bi]; all waves done with buf[bi^1]

      if (t + 1 < ntiles) {
        const int nkv0 = kv0 + 64;
        async16(kb + (size_t)(nkv0 + srow) * QKS + sgc * 8, Ks[bi ^ 1] + tid * 8);
        async16(vtb + (size_t)srow * Tn + nkv0 + sgc * 8, Vts[bi ^ 1] + tid * 8);
      }

      if (t > tdiag) continue;   // fully-masked for this wave (wave-uniform)

      // S = Q K^T (already log2-scaled via Q)
      const u16* ks = Ks[bi];
      const u16* vs = Vts[bi];
      f32x4 s[4];
#pragma unroll
      for (int nt = 0; nt < 4; ++nt) s[nt] = (f32x4){0.f, 0.f, 0.f, 0.f};
#pragma unroll
      for (int nt = 0; nt < 4; ++nt) {
        const int rb = nt * 16 + l16;
        ushx8 b0 = *(const ushx8*)(ks + rb * 64 + (quad ^ (rb & 7)) * 8);
        ushx8 b1 = *(const ushx8*)(ks + rb * 64 + ((quad + 4) ^ (rb & 7)) * 8);
        s[nt] = mfma_bf16(qf[0], b0, s[nt]);
        s[nt] = mfma_bf16(qf[1], b1, s[nt]);
      }

      // online softmax; mask only on the wave's single diagonal tile
      if (t == tdiag) {
#pragma unroll
        for (int i = 0; i < 4; ++i) {
          const int qr = q0w + quad * 4 + i;
          float vv[4];
          float rmax = -__builtin_inff();
#pragma unroll
          for (int nt = 0; nt < 4; ++nt) {
            float v = s[nt][i];
            if ((kv0 + nt * 16 + l16) > qr) v = -__builtin_inff();
            vv[nt] = v;
            rmax = fmaxf(rmax, v);
          }
          rmax = red16max(rmax);
          const float mnew = fmaxf(mrow[i], rmax);
          const float al = __builtin_amdgcn_exp2f(mrow[i] - mnew);
          mrow[i] = mnew;
          float rsum = 0.f;
#pragma unroll
          for (int nt = 0; nt < 4; ++nt) {
            float p = __builtin_amdgcn_exp2f(vv[nt] - mnew);
            rsum += p;
            pswv[(quad * 4 + i) * 72 + nt * 16 + l16] = f2bf_rna(p);
          }
          lrow[i] = lrow[i] * al + rsum;   // per-lane partial; reduced at end
#pragma unroll
          for (int nt = 0; nt < 4; ++nt) o[nt][i] *= al;
        }
      } else {
#pragma unroll
        for (int i = 0; i < 4; ++i) {
          float rmax = fmaxf(fmaxf(s[0][i], s[1][i]), fmaxf(s[2][i], s[3][i]));
          rmax = red16max(rmax);
          const float mnew = fmaxf(mrow[i], rmax);
          const float al = __builtin_amdgcn_exp2f(mrow[i] - mnew);
          mrow[i] = mnew;
          float rsum = 0.f;
#pragma unroll
          for (int nt = 0; nt < 4; ++nt) {
            float p = __builtin_amdgcn_exp2f(s[nt][i] - mnew);
            rsum += p;
            pswv[(quad * 4 + i) * 72 + nt * 16 + l16] = f2bf_rna(p);
          }
          lrow[i] = lrow[i] * al + rsum;
#pragma unroll
          for (int nt = 0; nt < 4; ++nt) o[nt][i] *= al;
        }
      }

      // P A-fragments from wave-local LDS (DS in-order per wave, no barrier)
      ushx8 pf0, pf1;
      {
        const u16* pp = pswv + l16 * 72 + quad * 8;
        pf0 = *(const ushx8*)pp;
        pf1 = *(const ushx8*)(pp + 32);
      }

      // O += P V
#pragma unroll
      for (int nt = 0; nt < 4; ++nt) {
        const int rb = nt * 16 + l16;
        ushx8 v0 = *(const ushx8*)(vs + rb * 64 + (quad ^ (rb & 7)) * 8);
        ushx8 v1 = *(const ushx8*)(vs + rb * 64 + ((quad + 4) ^ (rb & 7)) * 8);
        o[nt] = mfma_bf16(pf0, v0, o[nt]);
        o[nt] = mfma_bf16(pf1, v1, o[nt]);
      }
    }

    // O/l (16-lane l reduction deferred to here), write y_attn bf16
#pragma unroll
    for (int i = 0; i < 4; ++i) {
      const float inv = 1.f / red16sum(lrow[i]);
      const int trow = q0w + quad * 4 + i;
      u16* op = out + ((size_t)(b * Tn + trow)) * Cn + h * Dn + l16;
#pragma unroll
      for (int nt = 0; nt < 4; ++nt) op[nt * 16] = f2bf(o[nt][i] * inv);
    }
  }
}

// ---------------- launch ----------------
extern "C" void kernel_launch(void* const* d_in, const int* in_sizes, int n_in,
                              void* d_out, int out_size, void* d_ws, size_t ws_size,
                              hipStream_t stream) {
  const float* x = (const float*)d_in[0];
  const float* w_qkv = (const float*)d_in[1];
  const float* w_proj = (const float*)d_in[2];
  const float* b_proj = (const float*)d_in[3];
  float* out = (float*)d_out;
  char* ws = (char*)d_ws;

  u16* xb     = (u16*)(ws);                 // 16 MiB @ 0
  u16* wqkvb  = (u16*)(ws + 16777216);      //  6 MiB @ 16
  u16* wprojb = (u16*)(ws + 23068672);      //  2 MiB @ 22
  u16* qkb    = (u16*)(ws + 25165824);      // 32 MiB @ 24  (packed QK, stride 2048)
  u16* vtb    = (u16*)(ws + 58720256);      // 16 MiB @ 56
  u16* yb     = (u16*)(ws + 75497472);      // 16 MiB @ 72  (ends 88 MiB)

  cast3_kernel<<<12288, 256, 0, stream>>>(x, xb, 2097152,
                                          w_qkv, wqkvb, 786432,
                                          w_proj, wprojb, 262144);

  // QKV: 32 m-tiles x 24 n-tiles = 768 blocks; 2 blocks/CU -> 3 blocks per CU
  gemm_qkv_k<<<768, 512, 0, stream>>>(xb, wqkvb, qkb, vtb);

  attn_kernel<<<dim3(4, Hn, Bn), 512, 0, stream>>>(qkb, vtb, yb);

  // proj: 32 m-tiles x 8 n-tiles = 256 blocks
  gemm_proj_k<<<256, 512, 0, stream>>>(yb, wprojb, out, b_proj);
}

// Round 5
// 220.128 us; speedup vs baseline: 1.0189x; 1.0189x over previous
//
#include <hip/hip_runtime.h>
#include <stdint.h>

// MHA forward, B=8 T=1024 C=1024 H=16 D=64.
// cast3 -> QKV GEMM (256x128 tile, 4 waves/block, per-wave 128x64, 3-slot
// counted-vmcnt rotation, 72 KiB LDS -> 2 blocks/CU; 768 blocks)
// -> flash attention (512-thr blocks, 128-row q-tile pairs, peeled causal mask)
// -> proj GEMM (same body, BM=128 -> 512 blocks = 2/CU overlap, fp32 +bias).
// 4 launches. Kernel names split for per-stage profiling.

#define Bn 8
#define Tn 1024
#define Cn 1024
#define Hn 16
#define Dn 64
#define Mn (Bn * Tn)      // 8192
#define NQKV (3 * Cn)     // 3072
#define QKS 2048          // packed QK row stride

typedef unsigned short u16;
typedef float f32x4 __attribute__((ext_vector_type(4)));
typedef __bf16 bf16x8 __attribute__((ext_vector_type(8)));
typedef unsigned short ushx8 __attribute__((ext_vector_type(8)));
typedef unsigned short ushx4 __attribute__((ext_vector_type(4)));

__device__ __forceinline__ u16 f2bf(float f) {
  unsigned int u = __float_as_uint(f);
  u += 0x7fffu + ((u >> 16) & 1u);   // RTN-even
  return (u16)(u >> 16);
}
__device__ __forceinline__ u16 f2bf_rna(float f) {
  return (u16)((__float_as_uint(f) + 0x8000u) >> 16);
}

__device__ __forceinline__ f32x4 mfma_bf16(ushx8 a, ushx8 b, f32x4 c) {
  return __builtin_amdgcn_mfma_f32_16x16x32_bf16(
      __builtin_bit_cast(bf16x8, a), __builtin_bit_cast(bf16x8, b), c, 0, 0, 0);
}

// async global->LDS, 16B per lane; LDS dest = wave-uniform base + lane*16 (m104)
__device__ __forceinline__ void async16(const u16* g, u16* l) {
  __builtin_amdgcn_global_load_lds(
      (__attribute__((address_space(1))) void*)(void*)g,
      (__attribute__((address_space(3))) void*)l, 16, 0, 0);
}

// ---- DPP 16-lane butterfly reductions (VALU-rate, no LDS pipe) ----
template <int CTRL>
__device__ __forceinline__ float dppmov(float v) {
  return __builtin_bit_cast(float, __builtin_amdgcn_update_dpp(
      0, __builtin_bit_cast(int, v), CTRL, 0xf, 0xf, true));
}
__device__ __forceinline__ float red16max(float v) {
  v = fmaxf(v, dppmov<0xB1>(v));
  v = fmaxf(v, dppmov<0x4E>(v));
  v = fmaxf(v, dppmov<0x141>(v));
  v = fmaxf(v, dppmov<0x140>(v));
  return v;
}
__device__ __forceinline__ float red16sum(float v) {
  v += dppmov<0xB1>(v);
  v += dppmov<0x4E>(v);
  v += dppmov<0x141>(v);
  v += dppmov<0x140>(v);
  return v;
}

// ---------------- fused cast fp32 -> bf16 (3 tensors, 1 launch) ----------------
__global__ void cast3_kernel(const float* __restrict__ a, u16* __restrict__ oa, int na4,
                             const float* __restrict__ b, u16* __restrict__ ob, int nb4,
                             const float* __restrict__ c, u16* __restrict__ oc, int nc4) {
  int i = blockIdx.x * blockDim.x + threadIdx.x;
  const float* in;
  u16* out;
  if (i < na4) { in = a; out = oa; }
  else if (i < na4 + nb4) { in = b; out = ob; i -= na4; }
  else if (i < na4 + nb4 + nc4) { in = c; out = oc; i -= na4 + nb4; }
  else return;
  float4 v = ((const float4*)in)[i];
  ushx4 o = { f2bf(v.x), f2bf(v.y), f2bf(v.z), f2bf(v.w) };
  ((ushx4*)out)[i] = o;
}

#define SLOG2E 0.18033688011112042f

// ---------------- GEMM body: BMx128 tile, BK=64, 3-slot rotating pipeline ----------
// 256 threads = 4 waves (2M x 2N); per-wave (BM/2)x64 output = acc[BM/32][4].
// LDS 3*(BM*32 + 128*32) u16: A slots at 0, B slots at BBASE. Chunk swizzle
// p = q ^ ((row>>1)&3) on both stage-source and read (conflict-free, measured 0).
// BM=256: 72 KiB, 2 blocks/CU. BM=128: 48 KiB, grid gives 2 blocks/CU.
// Per-wave reads/phase: (BM/32 + 4) ds_read_b128 for (BM/32)*4 MFMA —
// 0.375 KB/MFMA at BM=256 (25% less LDS-read traffic than the 8-wave 64x64 map).
//
// Half-tiles h = 0..31 (K-tile h>>1, kk h&1); slot(h) = h % 3.
// Phase p: read slot p%3 (h=p); stage h'=min(p+2,31) into slot (p+2)%3
// (= slot read at p-1; its readers passed their lgkmcnt(0) before the p-1
// closing barrier); barrier; lgkmcnt(0); MFMA; vmcnt(LOADS); barrier.
// vmcnt(LOADS) at end-p drains phase p-1's LOADS loads -> phase p+1's data
// confirmed one phase ahead (~1300cy > 900cy HBM latency).
// Prologue: stage h0->slot0, h1->slot1; vmcnt(LOADS) confirms h0.
// Tail: stages clamp DATA to h=31; targets are slots whose readers are done.
// MODE=1: cols [0,2048)->packed QK (Q pre-scaled); [2048,3072)->V^T.
// MODE=0: fp32 out + bias (N = Cn).
template <int BM, int MODE>
__device__ __forceinline__ void gemm_body4(
    const u16* __restrict__ A, const u16* __restrict__ Bw,
    void* __restrict__ Cout, u16* __restrict__ vt,
    const float* __restrict__ bias) {
  constexpr int ASLOT = BM * 32;        // u16 per A slot
  constexpr int BSLOT = 128 * 32;       // u16 per B slot
  constexpr int BBASE = 3 * ASLOT;
  constexpr int ASW = BM / 64;          // async16 sweeps per A half (4 or 2)
  constexpr int BSW = 2;                // sweeps per B half
  constexpr int LOADS = ASW + BSW;      // DMA per phase (6 or 4)
  constexpr int MREP = BM / 32;         // per-wave M fragments (8 or 4)
  constexpr int MT = Mn / BM;           // m-tiles (32 or 64)
  constexpr int MPX = MT / 8;           // m-tiles per XCD (4 or 8, pow2)

  __shared__ alignas(16) u16 lds[3 * (ASLOT + BSLOT)];

  const int tid = threadIdx.x;
  const int lane = tid & 63;
  const int wv = tid >> 6;       // 0..3
  const int quad = lane >> 4;
  const int l16 = lane & 15;
  const int wr = wv >> 1;        // 0..1 (M)
  const int wc = wv & 1;         // 0..1 (N)

  // XCD chunk map: xcd = bid&7 owns MPX consecutive m-tiles x all n-tiles,
  // m-fastest (A chunk <= 2 MiB fits XCD L2; B panel reused MPX times).
  const int xcd = blockIdx.x & 7;
  const int loc = blockIdx.x >> 3;
  const int m0 = (xcd * MPX + (loc & (MPX - 1))) * BM;
  const int n0 = (loc / MPX) * 128;

  const u16* gA = A + (size_t)m0 * Cn;
  const u16* gB = Bw + (size_t)n0 * Cn;

  // staging source offsets per sweep: chunk c = s*256+tid -> row c>>2, stored
  // chunk c&3, global k-chunk q = (c&3) ^ ((row>>1)&3)  (XOR self-inverse)
  int soff[4];
#pragma unroll
  for (int s = 0; s < 4; ++s) {
    int c = s * 256 + tid;
    int row = c >> 2;
    int q = (c & 3) ^ ((row >> 1) & 3);
    soff[s] = row * Cn + q * 8;
  }

  auto stage = [&](int slot, int h) {
    const u16* sA = gA + (h >> 1) * 64 + (h & 1) * 32;
    u16* dA = lds + slot * ASLOT + tid * 8;
#pragma unroll
    for (int s = 0; s < ASW; ++s) async16(sA + soff[s], dA + s * 2048);
    const u16* sB = gB + (h >> 1) * 64 + (h & 1) * 32;
    u16* dB = lds + BBASE + slot * BSLOT + tid * 8;
#pragma unroll
    for (int s = 0; s < BSW; ++s) async16(sB + soff[s], dB + s * 2048);
  };

  // fragment read offsets (u16, within one half-region)
  const int sread = (quad ^ ((l16 >> 1) & 3)) * 8;
  const int aoff = (wr * (BM / 2) + l16) * 32 + sread;   // + mi*512 + slot*ASLOT
  const int boff = BBASE + (wc * 64 + l16) * 32 + sread; // + ni*512 + slot*BSLOT

  f32x4 acc[MREP][4];
#pragma unroll
  for (int i = 0; i < MREP; ++i)
#pragma unroll
    for (int j = 0; j < 4; ++j) acc[i][j] = (f32x4){0.f, 0.f, 0.f, 0.f};
  ushx8 af[MREP], bfr[4];

  // prologue: h0->slot0, h1->slot1; vmcnt(LOADS) confirms h0
  stage(0, 0);
  stage(1, 1);
  if constexpr (LOADS == 6) asm volatile("s_waitcnt vmcnt(6)" ::: "memory");
  else asm volatile("s_waitcnt vmcnt(4)" ::: "memory");
  __builtin_amdgcn_s_barrier();
  asm volatile("" ::: "memory");

#define PH(slot, sslot, hd)                                                    \
  {                                                                            \
    const u16* ab_ = lds + (slot) * ASLOT + aoff;                              \
    _Pragma("unroll") for (int mi_ = 0; mi_ < MREP; ++mi_)                     \
      af[mi_] = *(const ushx8*)(ab_ + mi_ * 512);                              \
    const u16* bb_ = lds + (slot) * BSLOT + boff;                              \
    _Pragma("unroll") for (int ni_ = 0; ni_ < 4; ++ni_)                        \
      bfr[ni_] = *(const ushx8*)(bb_ + ni_ * 512);                             \
    stage((sslot), (hd));                                                      \
    asm volatile("" ::: "memory");                                             \
    __builtin_amdgcn_s_barrier();                                              \
    asm volatile("s_waitcnt lgkmcnt(0)" ::: "memory");                         \
    __builtin_amdgcn_s_setprio(1);                                             \
    _Pragma("unroll") for (int mi_ = 0; mi_ < MREP; ++mi_) {                   \
      _Pragma("unroll") for (int ni_ = 0; ni_ < 4; ++ni_) {                    \
        acc[mi_][ni_] = mfma_bf16(af[mi_], bfr[ni_], acc[mi_][ni_]);           \
      }                                                                        \
    }                                                                          \
    __builtin_amdgcn_s_setprio(0);                                             \
    if constexpr (LOADS == 6)                                                  \
      asm volatile("s_waitcnt vmcnt(6)" ::: "memory");                         \
    else                                                                       \
      asm volatile("s_waitcnt vmcnt(4)" ::: "memory");                         \
    asm volatile("" ::: "memory");                                             \
    __builtin_amdgcn_s_barrier();                                              \
    asm volatile("" ::: "memory");                                             \
  }

  // phases 0..29: five groups of 6 (slot pattern 0,1,2,0,1,2)
#pragma unroll 1
  for (int it = 0; it < 5; ++it) {
    const int p = it * 6;
    PH(0, 2, p + 2)
    PH(1, 0, p + 3)
    PH(2, 1, p + 4)
    PH(0, 2, p + 5)
    PH(1, 0, p + 6)
    PH(2, 1, p + 7)
  }
  // tail: phases 30, 31 (stages clamp to h=31; targets never read again)
  PH(0, 2, 31)
  PH(1, 0, 31)
#undef PH
  asm volatile("s_waitcnt vmcnt(0)" ::: "memory");

  // epilogue
  if constexpr (MODE) {
    if (n0 < 2 * Cn) {
      const float sc = (n0 < Cn) ? SLOG2E : 1.f;
#pragma unroll
      for (int mi = 0; mi < MREP; ++mi) {
#pragma unroll
        for (int ni = 0; ni < 4; ++ni) {
          const int col = n0 + wc * 64 + ni * 16 + l16;
          const int row = m0 + wr * (BM / 2) + mi * 16 + quad * 4;
#pragma unroll
          for (int i = 0; i < 4; ++i)
            ((u16*)Cout)[(size_t)(row + i) * QKS + col] = f2bf(acc[mi][ni][i] * sc);
        }
      }
    } else {
#pragma unroll
      for (int mi = 0; mi < MREP; ++mi) {
#pragma unroll
        for (int ni = 0; ni < 4; ++ni) {
          const int colV = n0 - 2 * Cn + wc * 64 + ni * 16 + l16;  // 0..1023
          const int hh = colV >> 6, dd = colV & 63;
          const int row0 = m0 + wr * (BM / 2) + mi * 16 + quad * 4;
          const int bb = row0 >> 10, tt = row0 & 1023;
          unsigned int lo = (unsigned int)f2bf(acc[mi][ni][0]) |
                            ((unsigned int)f2bf(acc[mi][ni][1]) << 16);
          unsigned int hi = (unsigned int)f2bf(acc[mi][ni][2]) |
                            ((unsigned int)f2bf(acc[mi][ni][3]) << 16);
          uint2 pk = {lo, hi};
          *(uint2*)&vt[((size_t)(bb * Hn + hh) * Dn + dd) * Tn + tt] = pk;
        }
      }
    }
  } else {
#pragma unroll
    for (int mi = 0; mi < MREP; ++mi) {
#pragma unroll
      for (int ni = 0; ni < 4; ++ni) {
        const int col = n0 + wc * 64 + ni * 16 + l16;
        const float bv = bias[col];
        const int row = m0 + wr * (BM / 2) + mi * 16 + quad * 4;
#pragma unroll
        for (int i = 0; i < 4; ++i)
          ((float*)Cout)[(size_t)(row + i) * Cn + col] = acc[mi][ni][i] + bv;
      }
    }
  }
}

// named wrappers so rocprof separates the two GEMMs
__global__ __launch_bounds__(256, 2) void gemm_qkv_k(
    const u16* __restrict__ A, const u16* __restrict__ Bw,
    u16* __restrict__ qk, u16* __restrict__ vt) {
  gemm_body4<256, 1>(A, Bw, (void*)qk, vt, nullptr);
}
__global__ __launch_bounds__(256, 2) void gemm_proj_k(
    const u16* __restrict__ A, const u16* __restrict__ Bw,
    float* __restrict__ out, const float* __restrict__ bias) {
  gemm_body4<128, 0>(A, Bw, (void*)out, nullptr, bias);
}

// ---------------- flash attention v5 ----------------
// 512 blocks (4,16,8) x 512 threads (8 waves). Block j does 128-row q-tiles
// j and 7-j (18 kv-tiles total — balanced, 2 blocks/CU = 16 waves/CU).
// Wave wv owns q rows [wv*16, wv*16+16). Per wave one diagonal kv-tile.
// Double-buffered async K/V^T staging; DPP reductions; raw v_exp_f32;
// per-lane l partials reduced once per phase. QK stride 2048, Q pre-scaled.
__global__ __launch_bounds__(512, 4) void attn_kernel(
    const u16* __restrict__ qk, const u16* __restrict__ vt,
    u16* __restrict__ out) {
  const int j = blockIdx.x, h = blockIdx.y, b = blockIdx.z;
  const int tid = threadIdx.x;
  const int lane = tid & 63;
  const int wv = tid >> 6;           // 0..7
  const int quad = lane >> 4;
  const int l16 = lane & 15;

  __shared__ alignas(16) u16 Ks[2][64 * 64];   // [buf][kv][d] XOR-swizzled
  __shared__ alignas(16) u16 Vts[2][64 * 64];  // [buf][d][kv] XOR-swizzled
  __shared__ alignas(16) u16 Ps[8][16 * 72];   // per-wave P

  const u16* qb = qk + (size_t)b * Tn * QKS + h * Dn;
  const u16* kb = qk + (size_t)b * Tn * QKS + Cn + h * Dn;
  const u16* vtb = vt + (size_t)(b * Hn + h) * Dn * Tn;

  const int srow = tid >> 3;  // 0..63
  const int scc = tid & 7;
  const int sgc = scc ^ (srow & 7);
  u16* pswv = Ps[wv];

#pragma unroll 1
  for (int ph = 0; ph < 2; ++ph) {
    const int qt = ph ? (7 - j) : j;
    const int q0w = qt * 128 + wv * 16;   // this wave's first q row
    const int ntiles = 2 * qt + 2;
    const int tdiag = q0w >> 6;           // in-phase diagonal tile index

    // Q fragments (A-operand: m=l16, k=quad*8+jj); already scaled by SLOG2E
    ushx8 qf[2];
    {
      const u16* qp = qb + (size_t)(q0w + l16) * QKS + quad * 8;
      qf[0] = *(const ushx8*)qp;
      qf[1] = *(const ushx8*)(qp + 32);
    }

    f32x4 o[4];
#pragma unroll
    for (int nt = 0; nt < 4; ++nt) o[nt] = (f32x4){0.f, 0.f, 0.f, 0.f};
    float mrow[4], lrow[4];
#pragma unroll
    for (int i = 0; i < 4; ++i) { mrow[i] = -__builtin_inff(); lrow[i] = 0.f; }

    __syncthreads();  // previous phase's compute done before overwriting buf0

    // prefetch tile 0 -> buf 0 (one 16B DMA per thread per buffer)
    async16(kb + (size_t)srow * QKS + sgc * 8, Ks[0] + tid * 8);
    async16(vtb + (size_t)srow * Tn + sgc * 8, Vts[0] + tid * 8);

#pragma unroll 1
    for (int t = 0; t < ntiles; ++t) {
      const int kv0 = t * 64;
      const int bi = t & 1;
      __syncthreads();  // drains DMA for buf[bi]; all waves done with buf[bi^1]

      if (t + 1 < ntiles) {
        const int nkv0 = kv0 + 64;
        async16(kb + (size_t)(nkv0 + srow) * QKS + sgc * 8, Ks[bi ^ 1] + tid * 8);
        async16(vtb + (size_t)srow * Tn + nkv0 + sgc * 8, Vts[bi ^ 1] + tid * 8);
      }

      if (t > tdiag) continue;   // fully-masked for this wave (wave-uniform)

      // S = Q K^T (already log2-scaled via Q)
      const u16* ks = Ks[bi];
      const u16* vs = Vts[bi];
      f32x4 s[4];
#pragma unroll
      for (int nt = 0; nt < 4; ++nt) s[nt] = (f32x4){0.f, 0.f, 0.f, 0.f};
#pragma unroll
      for (int nt = 0; nt < 4; ++nt) {
        const int rb = nt * 16 + l16;
        ushx8 b0 = *(const ushx8*)(ks + rb * 64 + (quad ^ (rb & 7)) * 8);
        ushx8 b1 = *(const ushx8*)(ks + rb * 64 + ((quad + 4) ^ (rb & 7)) * 8);
        s[nt] = mfma_bf16(qf[0], b0, s[nt]);
        s[nt] = mfma_bf16(qf[1], b1, s[nt]);
      }

      // online softmax; mask only on the wave's single diagonal tile
      if (t == tdiag) {
#pragma unroll
        for (int i = 0; i < 4; ++i) {
          const int qr = q0w + quad * 4 + i;
          float vv[4];
          float rmax = -__builtin_inff();
#pragma unroll
          for (int nt = 0; nt < 4; ++nt) {
            float v = s[nt][i];
            if ((kv0 + nt * 16 + l16) > qr) v = -__builtin_inff();
            vv[nt] = v;
            rmax = fmaxf(rmax, v);
          }
          rmax = red16max(rmax);
          const float mnew = fmaxf(mrow[i], rmax);
          const float al = __builtin_amdgcn_exp2f(mrow[i] - mnew);
          mrow[i] = mnew;
          float rsum = 0.f;
#pragma unroll
          for (int nt = 0; nt < 4; ++nt) {
            float p = __builtin_amdgcn_exp2f(vv[nt] - mnew);
            rsum += p;
            pswv[(quad * 4 + i) * 72 + nt * 16 + l16] = f2bf_rna(p);
          }
          lrow[i] = lrow[i] * al + rsum;   // per-lane partial; reduced at end
#pragma unroll
          for (int nt = 0; nt < 4; ++nt) o[nt][i] *= al;
        }
      } else {
#pragma unroll
        for (int i = 0; i < 4; ++i) {
          float rmax = fmaxf(fmaxf(s[0][i], s[1][i]), fmaxf(s[2][i], s[3][i]));
          rmax = red16max(rmax);
          const float mnew = fmaxf(mrow[i], rmax);
          const float al = __builtin_amdgcn_exp2f(mrow[i] - mnew);
          mrow[i] = mnew;
          float rsum = 0.f;
#pragma unroll
          for (int nt = 0; nt < 4; ++nt) {
            float p = __builtin_amdgcn_exp2f(s[nt][i] - mnew);
            rsum += p;
            pswv[(quad * 4 + i) * 72 + nt * 16 + l16] = f2bf_rna(p);
          }
          lrow[i] = lrow[i] * al + rsum;
#pragma unroll
          for (int nt = 0; nt < 4; ++nt) o[nt][i] *= al;
        }
      }

      // P A-fragments from wave-local LDS (DS in-order per wave, no barrier)
      ushx8 pf0, pf1;
      {
        const u16* pp = pswv + l16 * 72 + quad * 8;
        pf0 = *(const ushx8*)pp;
        pf1 = *(const ushx8*)(pp + 32);
      }

      // O += P V
#pragma unroll
      for (int nt = 0; nt < 4; ++nt) {
        const int rb = nt * 16 + l16;
        ushx8 v0 = *(const ushx8*)(vs + rb * 64 + (quad ^ (rb & 7)) * 8);
        ushx8 v1 = *(const ushx8*)(vs + rb * 64 + ((quad + 4) ^ (rb & 7)) * 8);
        o[nt] = mfma_bf16(pf0, v0, o[nt]);
        o[nt] = mfma_bf16(pf1, v1, o[nt]);
      }
    }

    // O/l (16-lane l reduction deferred to here), write y_attn bf16
#pragma unroll
    for (int i = 0; i < 4; ++i) {
      const float inv = 1.f / red16sum(lrow[i]);
      const int trow = q0w + quad * 4 + i;
      u16* op = out + ((size_t)(b * Tn + trow)) * Cn + h * Dn + l16;
#pragma unroll
      for (int nt = 0; nt < 4; ++nt) op[nt * 16] = f2bf(o[nt][i] * inv);
    }
  }
}

// ---------------- launch ----------------
extern "C" void kernel_launch(void* const* d_in, const int* in_sizes, int n_in,
                              void* d_out, int out_size, void* d_ws, size_t ws_size,
                              hipStream_t stream) {
  const float* x = (const float*)d_in[0];
  const float* w_qkv = (const float*)d_in[1];
  const float* w_proj = (const float*)d_in[2];
  const float* b_proj = (const float*)d_in[3];
  float* out = (float*)d_out;
  char* ws = (char*)d_ws;

  u16* xb     = (u16*)(ws);                 // 16 MiB @ 0
  u16* wqkvb  = (u16*)(ws + 16777216);      //  6 MiB @ 16
  u16* wprojb = (u16*)(ws + 23068672);      //  2 MiB @ 22
  u16* qkb    = (u16*)(ws + 25165824);      // 32 MiB @ 24  (packed QK, stride 2048)
  u16* vtb    = (u16*)(ws + 58720256);      // 16 MiB @ 56
  u16* yb     = (u16*)(ws + 75497472);      // 16 MiB @ 72  (ends 88 MiB)

  cast3_kernel<<<12288, 256, 0, stream>>>(x, xb, 2097152,
                                          w_qkv, wqkvb, 786432,
                                          w_proj, wprojb, 262144);

  // QKV: 32 m-tiles x 24 n-tiles = 768 blocks (256 thr, 2 blocks/CU)
  gemm_qkv_k<<<768, 256, 0, stream>>>(xb, wqkvb, qkb, vtb);

  attn_kernel<<<dim3(4, Hn, Bn), 512, 0, stream>>>(qkb, vtb, yb);

  // proj: 64 m-tiles x 8 n-tiles = 512 blocks (256 thr, 2 blocks/CU)
  gemm_proj_k<<<512, 256, 0, stream>>>(yb, wprojb, out, b_proj);
}

// Round 6
// 214.115 us; speedup vs baseline: 1.0475x; 1.0281x over previous
//
#include <hip/hip_runtime.h>
#include <stdint.h>

// MHA forward, B=8 T=1024 C=1024 H=16 D=64.
// cast3 -> QKV GEMM (R4-best: 256x128 tile, 8 waves/512thr, 3-slot rotation,
// counted vmcnt, 72 KiB -> 2 blocks/CU, 768 blocks)
// -> flash attention (3-slot K/V rotation + tile-PAIR pipelining: QK^T(t+1)
// hoisted over softmax(t) so MFMA overlaps the VALU/P-LDS chain)
// -> proj GEMM (R5-best: BM=128, 4 waves, 512 blocks = 2/CU, fp32 +bias).
// 4 launches.

#define Bn 8
#define Tn 1024
#define Cn 1024
#define Hn 16
#define Dn 64
#define Mn (Bn * Tn)      // 8192
#define NQKV (3 * Cn)     // 3072
#define QKS 2048          // packed QK row stride

typedef unsigned short u16;
typedef float f32x4 __attribute__((ext_vector_type(4)));
typedef __bf16 bf16x8 __attribute__((ext_vector_type(8)));
typedef unsigned short ushx8 __attribute__((ext_vector_type(8)));
typedef unsigned short ushx4 __attribute__((ext_vector_type(4)));

__device__ __forceinline__ u16 f2bf(float f) {
  unsigned int u = __float_as_uint(f);
  u += 0x7fffu + ((u >> 16) & 1u);   // RTN-even
  return (u16)(u >> 16);
}
__device__ __forceinline__ u16 f2bf_rna(float f) {
  return (u16)((__float_as_uint(f) + 0x8000u) >> 16);
}

__device__ __forceinline__ f32x4 mfma_bf16(ushx8 a, ushx8 b, f32x4 c) {
  return __builtin_amdgcn_mfma_f32_16x16x32_bf16(
      __builtin_bit_cast(bf16x8, a), __builtin_bit_cast(bf16x8, b), c, 0, 0, 0);
}

// async global->LDS, 16B per lane; LDS dest = wave-uniform base + lane*16 (m104)
__device__ __forceinline__ void async16(const u16* g, u16* l) {
  __builtin_amdgcn_global_load_lds(
      (__attribute__((address_space(1))) void*)(void*)g,
      (__attribute__((address_space(3))) void*)l, 16, 0, 0);
}

// ---- DPP 16-lane butterfly reductions (VALU-rate, no LDS pipe) ----
template <int CTRL>
__device__ __forceinline__ float dppmov(float v) {
  return __builtin_bit_cast(float, __builtin_amdgcn_update_dpp(
      0, __builtin_bit_cast(int, v), CTRL, 0xf, 0xf, true));
}
__device__ __forceinline__ float red16max(float v) {
  v = fmaxf(v, dppmov<0xB1>(v));
  v = fmaxf(v, dppmov<0x4E>(v));
  v = fmaxf(v, dppmov<0x141>(v));
  v = fmaxf(v, dppmov<0x140>(v));
  return v;
}
__device__ __forceinline__ float red16sum(float v) {
  v += dppmov<0xB1>(v);
  v += dppmov<0x4E>(v);
  v += dppmov<0x141>(v);
  v += dppmov<0x140>(v);
  return v;
}

// ---------------- fused cast fp32 -> bf16 (3 tensors, 1 launch) ----------------
__global__ void cast3_kernel(const float* __restrict__ a, u16* __restrict__ oa, int na4,
                             const float* __restrict__ b, u16* __restrict__ ob, int nb4,
                             const float* __restrict__ c, u16* __restrict__ oc, int nc4) {
  int i = blockIdx.x * blockDim.x + threadIdx.x;
  const float* in;
  u16* out;
  if (i < na4) { in = a; out = oa; }
  else if (i < na4 + nb4) { in = b; out = ob; i -= na4; }
  else if (i < na4 + nb4 + nc4) { in = c; out = oc; i -= na4 + nb4; }
  else return;
  float4 v = ((const float4*)in)[i];
  ushx4 o = { f2bf(v.x), f2bf(v.y), f2bf(v.z), f2bf(v.w) };
  ((ushx4*)out)[i] = o;
}

#define SLOG2E 0.18033688011112042f

// ---------------- QKV GEMM body (R4-best): 256x128, 8 waves, 3-slot rotation ----------
// 512 threads = 8 waves (4 M x 2 N); per-wave 64x64 output = acc[4][4].
// LDS 72 KiB: A = 3 slots x [256][32] u16 at 0; B = 3 slots x [128][32] at
// +24576 u16. Chunk swizzle p = q ^ ((row>>1)&3) (conflict-free, measured 0).
// 2 blocks/CU: partner block's MFMA covers this block's drain stalls.
// Phase p: read slot p%3 (h=p); stage h'=min(p+2,31) into slot (p+2)%3;
// barrier; lgkmcnt(0); 16 MFMA; vmcnt(3); barrier.  (Invariants: restage lands
// 1 phase after slot's last read; staging confirmed 1 phase before its read.)
template <int MODE>
__device__ __forceinline__ void gemm_body(
    const u16* __restrict__ A, const u16* __restrict__ Bw,
    void* __restrict__ Cout, u16* __restrict__ vt,
    const float* __restrict__ bias) {
  __shared__ alignas(16) u16 lds[36864];  // 72 KiB

  const int tid = threadIdx.x;
  const int lane = tid & 63;
  const int wv = tid >> 6;       // 0..7
  const int quad = lane >> 4;
  const int l16 = lane & 15;
  const int wr = wv >> 1;        // 0..3 (M)
  const int wc = wv & 1;         // 0..1 (N)

  // XCD chunk map: xcd = bid&7 owns 4 consecutive 256-row m-tiles x all
  // n-tiles, m-fastest (A chunk 2 MiB fits XCD L2; B panel reused 4x).
  const int xcd = blockIdx.x & 7;
  const int loc = blockIdx.x >> 3;
  const int m0 = (xcd * 4 + (loc & 3)) * 256;
  const int n0 = (loc >> 2) * 128;

  const u16* gA = A + (size_t)m0 * Cn;
  const u16* gB = Bw + (size_t)n0 * Cn;

  const int r0s = tid >> 2;
  const int q0s = (tid & 3) ^ ((r0s >> 1) & 3);
  const int c1s = 512 + tid;
  const int r1s = c1s >> 2;
  const int q1s = (c1s & 3) ^ ((r1s >> 1) & 3);
  const int so0 = r0s * Cn + q0s * 8;
  const int so1 = r1s * Cn + q1s * 8;

  auto stageA = [&](int slot, int h) {
    u16* dst = lds + slot * 8192 + tid * 8;
    const u16* src = gA + (h >> 1) * 64 + (h & 1) * 32;
    async16(src + so0, dst);
    async16(src + so1, dst + 4096);
  };
  auto stageB = [&](int slot, int h) {
    u16* dst = lds + 24576 + slot * 4096 + tid * 8;
    const u16* src = gB + (h >> 1) * 64 + (h & 1) * 32;
    async16(src + so0, dst);
  };

  const int sread = (quad ^ ((l16 >> 1) & 3)) * 8;
  const int aoff = (wr * 64 + l16) * 32 + sread;
  const int boff = 24576 + (wc * 64 + l16) * 32 + sread;

  f32x4 acc[4][4];
#pragma unroll
  for (int i = 0; i < 4; ++i)
#pragma unroll
    for (int jj = 0; jj < 4; ++jj) acc[i][jj] = (f32x4){0.f, 0.f, 0.f, 0.f};
  ushx8 af[4], bfr[4];

  stageA(0, 0); stageB(0, 0);
  stageA(1, 1); stageB(1, 1);
  asm volatile("s_waitcnt vmcnt(3)" ::: "memory");
  __builtin_amdgcn_s_barrier();
  asm volatile("" ::: "memory");

#define PH(slot, sslot, hd)                                                    \
  {                                                                            \
    const u16* ab_ = lds + (slot) * 8192 + aoff;                               \
    af[0] = *(const ushx8*)(ab_);                                              \
    af[1] = *(const ushx8*)(ab_ + 512);                                        \
    af[2] = *(const ushx8*)(ab_ + 1024);                                       \
    af[3] = *(const ushx8*)(ab_ + 1536);                                       \
    const u16* bb_ = lds + (slot) * 4096 + boff;                               \
    bfr[0] = *(const ushx8*)(bb_);                                             \
    bfr[1] = *(const ushx8*)(bb_ + 512);                                       \
    bfr[2] = *(const ushx8*)(bb_ + 1024);                                      \
    bfr[3] = *(const ushx8*)(bb_ + 1536);                                      \
    stageA((sslot), (hd));                                                     \
    stageB((sslot), (hd));                                                     \
    asm volatile("" ::: "memory");                                             \
    __builtin_amdgcn_s_barrier();                                              \
    asm volatile("s_waitcnt lgkmcnt(0)" ::: "memory");                         \
    __builtin_amdgcn_s_setprio(1);                                             \
    _Pragma("unroll") for (int mi_ = 0; mi_ < 4; ++mi_) {                      \
      _Pragma("unroll") for (int ni_ = 0; ni_ < 4; ++ni_) {                    \
        acc[mi_][ni_] = mfma_bf16(af[mi_], bfr[ni_], acc[mi_][ni_]);           \
      }                                                                        \
    }                                                                          \
    __builtin_amdgcn_s_setprio(0);                                             \
    asm volatile("s_waitcnt vmcnt(3)" ::: "memory");                           \
    asm volatile("" ::: "memory");                                             \
    __builtin_amdgcn_s_barrier();                                              \
    asm volatile("" ::: "memory");                                             \
  }

#pragma unroll 1
  for (int it = 0; it < 5; ++it) {
    const int p = it * 6;
    PH(0, 2, p + 2)
    PH(1, 0, p + 3)
    PH(2, 1, p + 4)
    PH(0, 2, p + 5)
    PH(1, 0, p + 6)
    PH(2, 1, p + 7)
  }
  PH(0, 2, 31)
  PH(1, 0, 31)
#undef PH
  asm volatile("s_waitcnt vmcnt(0)" ::: "memory");

  if constexpr (MODE) {
    if (n0 < 2 * Cn) {
      const float sc = (n0 < Cn) ? SLOG2E : 1.f;
#pragma unroll
      for (int mi = 0; mi < 4; ++mi) {
#pragma unroll
        for (int ni = 0; ni < 4; ++ni) {
          const int col = n0 + wc * 64 + ni * 16 + l16;
          const int row = m0 + wr * 64 + mi * 16 + quad * 4;
#pragma unroll
          for (int i = 0; i < 4; ++i)
            ((u16*)Cout)[(size_t)(row + i) * QKS + col] = f2bf(acc[mi][ni][i] * sc);
        }
      }
    } else {
#pragma unroll
      for (int mi = 0; mi < 4; ++mi) {
#pragma unroll
        for (int ni = 0; ni < 4; ++ni) {
          const int colV = n0 - 2 * Cn + wc * 64 + ni * 16 + l16;  // 0..1023
          const int hh = colV >> 6, dd = colV & 63;
          const int row0 = m0 + wr * 64 + mi * 16 + quad * 4;
          const int bb = row0 >> 10, tt = row0 & 1023;
          unsigned int lo = (unsigned int)f2bf(acc[mi][ni][0]) |
                            ((unsigned int)f2bf(acc[mi][ni][1]) << 16);
          unsigned int hi = (unsigned int)f2bf(acc[mi][ni][2]) |
                            ((unsigned int)f2bf(acc[mi][ni][3]) << 16);
          uint2 pk = {lo, hi};
          *(uint2*)&vt[((size_t)(bb * Hn + hh) * Dn + dd) * Tn + tt] = pk;
        }
      }
    }
  } else {
#pragma unroll
    for (int mi = 0; mi < 4; ++mi) {
#pragma unroll
      for (int ni = 0; ni < 4; ++ni) {
        const int col = n0 + wc * 64 + ni * 16 + l16;
        const float bv = bias[col];
        const int row = m0 + wr * 64 + mi * 16 + quad * 4;
#pragma unroll
        for (int i = 0; i < 4; ++i)
          ((float*)Cout)[(size_t)(row + i) * Cn + col] = acc[mi][ni][i] + bv;
      }
    }
  }
}

// ---------------- proj GEMM body (R5-best): BM=128, 4 waves, 3-slot rotation ------
template <int BM, int MODE>
__device__ __forceinline__ void gemm_body4(
    const u16* __restrict__ A, const u16* __restrict__ Bw,
    void* __restrict__ Cout, u16* __restrict__ vt,
    const float* __restrict__ bias) {
  constexpr int ASLOT = BM * 32;
  constexpr int BSLOT = 128 * 32;
  constexpr int BBASE = 3 * ASLOT;
  constexpr int ASW = BM / 64;
  constexpr int BSW = 2;
  constexpr int LOADS = ASW + BSW;
  constexpr int MREP = BM / 32;
  constexpr int MT = Mn / BM;
  constexpr int MPX = MT / 8;

  __shared__ alignas(16) u16 lds[3 * (ASLOT + BSLOT)];

  const int tid = threadIdx.x;
  const int lane = tid & 63;
  const int wv = tid >> 6;
  const int quad = lane >> 4;
  const int l16 = lane & 15;
  const int wr = wv >> 1;
  const int wc = wv & 1;

  const int xcd = blockIdx.x & 7;
  const int loc = blockIdx.x >> 3;
  const int m0 = (xcd * MPX + (loc & (MPX - 1))) * BM;
  const int n0 = (loc / MPX) * 128;

  const u16* gA = A + (size_t)m0 * Cn;
  const u16* gB = Bw + (size_t)n0 * Cn;

  int soff[4];
#pragma unroll
  for (int s = 0; s < 4; ++s) {
    int c = s * 256 + tid;
    int row = c >> 2;
    int q = (c & 3) ^ ((row >> 1) & 3);
    soff[s] = row * Cn + q * 8;
  }

  auto stage = [&](int slot, int h) {
    const u16* sA = gA + (h >> 1) * 64 + (h & 1) * 32;
    u16* dA = lds + slot * ASLOT + tid * 8;
#pragma unroll
    for (int s = 0; s < ASW; ++s) async16(sA + soff[s], dA + s * 2048);
    const u16* sB = gB + (h >> 1) * 64 + (h & 1) * 32;
    u16* dB = lds + BBASE + slot * BSLOT + tid * 8;
#pragma unroll
    for (int s = 0; s < BSW; ++s) async16(sB + soff[s], dB + s * 2048);
  };

  const int sread = (quad ^ ((l16 >> 1) & 3)) * 8;
  const int aoff = (wr * (BM / 2) + l16) * 32 + sread;
  const int boff = BBASE + (wc * 64 + l16) * 32 + sread;

  f32x4 acc[MREP][4];
#pragma unroll
  for (int i = 0; i < MREP; ++i)
#pragma unroll
    for (int jj = 0; jj < 4; ++jj) acc[i][jj] = (f32x4){0.f, 0.f, 0.f, 0.f};
  ushx8 af[MREP], bfr[4];

  stage(0, 0);
  stage(1, 1);
  if constexpr (LOADS == 6) asm volatile("s_waitcnt vmcnt(6)" ::: "memory");
  else asm volatile("s_waitcnt vmcnt(4)" ::: "memory");
  __builtin_amdgcn_s_barrier();
  asm volatile("" ::: "memory");

#define PH(slot, sslot, hd)                                                    \
  {                                                                            \
    const u16* ab_ = lds + (slot) * ASLOT + aoff;                              \
    _Pragma("unroll") for (int mi_ = 0; mi_ < MREP; ++mi_)                     \
      af[mi_] = *(const ushx8*)(ab_ + mi_ * 512);                              \
    const u16* bb_ = lds + (slot) * BSLOT + boff;                              \
    _Pragma("unroll") for (int ni_ = 0; ni_ < 4; ++ni_)                        \
      bfr[ni_] = *(const ushx8*)(bb_ + ni_ * 512);                             \
    stage((sslot), (hd));                                                      \
    asm volatile("" ::: "memory");                                             \
    __builtin_amdgcn_s_barrier();                                              \
    asm volatile("s_waitcnt lgkmcnt(0)" ::: "memory");                         \
    __builtin_amdgcn_s_setprio(1);                                             \
    _Pragma("unroll") for (int mi_ = 0; mi_ < MREP; ++mi_) {                   \
      _Pragma("unroll") for (int ni_ = 0; ni_ < 4; ++ni_) {                    \
        acc[mi_][ni_] = mfma_bf16(af[mi_], bfr[ni_], acc[mi_][ni_]);           \
      }                                                                        \
    }                                                                          \
    __builtin_amdgcn_s_setprio(0);                                             \
    if constexpr (LOADS == 6)                                                  \
      asm volatile("s_waitcnt vmcnt(6)" ::: "memory");                         \
    else                                                                       \
      asm volatile("s_waitcnt vmcnt(4)" ::: "memory");                         \
    asm volatile("" ::: "memory");                                             \
    __builtin_amdgcn_s_barrier();                                              \
    asm volatile("" ::: "memory");                                             \
  }

#pragma unroll 1
  for (int it = 0; it < 5; ++it) {
    const int p = it * 6;
    PH(0, 2, p + 2)
    PH(1, 0, p + 3)
    PH(2, 1, p + 4)
    PH(0, 2, p + 5)
    PH(1, 0, p + 6)
    PH(2, 1, p + 7)
  }
  PH(0, 2, 31)
  PH(1, 0, 31)
#undef PH
  asm volatile("s_waitcnt vmcnt(0)" ::: "memory");

  if constexpr (MODE) {
    // (unused in this launch config)
  } else {
#pragma unroll
    for (int mi = 0; mi < MREP; ++mi) {
#pragma unroll
      for (int ni = 0; ni < 4; ++ni) {
        const int col = n0 + wc * 64 + ni * 16 + l16;
        const float bv = bias[col];
        const int row = m0 + wr * (BM / 2) + mi * 16 + quad * 4;
#pragma unroll
        for (int i = 0; i < 4; ++i)
          ((float*)Cout)[(size_t)(row + i) * Cn + col] = acc[mi][ni][i] + bv;
      }
    }
  }
}

__global__ __launch_bounds__(512, 4) void gemm_qkv_k(
    const u16* __restrict__ A, const u16* __restrict__ Bw,
    u16* __restrict__ qk, u16* __restrict__ vt) {
  gemm_body<1>(A, Bw, (void*)qk, vt, nullptr);
}
__global__ __launch_bounds__(256, 2) void gemm_proj_k(
    const u16* __restrict__ A, const u16* __restrict__ Bw,
    float* __restrict__ out, const float* __restrict__ bias) {
  gemm_body4<128, 0>(A, Bw, (void*)out, nullptr, bias);
}

// ---------------- flash attention v6: 3-slot K/V rotation + tile-pair pipeline ----
// 512 blocks (4,16,8) x 512 threads (8 waves). Block j does 128-row q-tiles
// j and 7-j. Wave wv owns q rows [wv*16, wv*16+16); one diagonal kv-tile each.
// K/V in 3 LDS slots (slot = tile % 3): at a pair (t,t+1)'s top barrier BOTH
// tiles are staged-and-drained, so QK^T(t+1) issues before softmax(t) —
// its MFMA overlaps softmax's VALU chain and P(t)'s LDS write->read latency.
// Rotation invariants: stage t+2 -> slot (t+2)%3 (last read pair t-2, behind
// top barrier); stage t+3 -> slot t%3 after mid-pair barrier (its readers,
// QK/PV of t, are done). __syncthreads drains each wave's own DMA (vmcnt 0).
// LDS: 3*(8K+8K)=48K + P 18.4K = 66.4 KiB -> 2 blocks/CU.
__global__ __launch_bounds__(512, 4) void attn_kernel(
    const u16* __restrict__ qk, const u16* __restrict__ vt,
    u16* __restrict__ out) {
  const int j = blockIdx.x, h = blockIdx.y, b = blockIdx.z;
  const int tid = threadIdx.x;
  const int lane = tid & 63;
  const int wv = tid >> 6;           // 0..7
  const int quad = lane >> 4;
  const int l16 = lane & 15;

  __shared__ alignas(16) u16 Ks[3][64 * 64];   // [slot][kv][d] XOR-swizzled
  __shared__ alignas(16) u16 Vts[3][64 * 64];  // [slot][d][kv] XOR-swizzled
  __shared__ alignas(16) u16 Ps[8][16 * 72];   // per-wave P

  const u16* qb = qk + (size_t)b * Tn * QKS + h * Dn;
  const u16* kb = qk + (size_t)b * Tn * QKS + Cn + h * Dn;
  const u16* vtb = vt + (size_t)(b * Hn + h) * Dn * Tn;

  const int srow = tid >> 3;  // 0..63
  const int sgc = (tid & 7) ^ (srow & 7);
  u16* pswv = Ps[wv];

  auto stageKV = [&](int slot, int kt) {
    const int kv0s = kt * 64;
    async16(kb + (size_t)(kv0s + srow) * QKS + sgc * 8, Ks[slot] + tid * 8);
    async16(vtb + (size_t)srow * Tn + kv0s + sgc * 8, Vts[slot] + tid * 8);
  };

#pragma unroll 1
  for (int ph = 0; ph < 2; ++ph) {
    const int qt = ph ? (7 - j) : j;
    const int q0w = qt * 128 + wv * 16;   // this wave's first q row
    const int ntiles = 2 * qt + 2;        // even
    const int tdiag = q0w >> 6;           // wave's diagonal tile index

    // Q fragments (A-operand: m=l16, k=quad*8+jj); already scaled by SLOG2E
    ushx8 qf[2];
    {
      const u16* qp = qb + (size_t)(q0w + l16) * QKS + quad * 8;
      qf[0] = *(const ushx8*)qp;
      qf[1] = *(const ushx8*)(qp + 32);
    }

    f32x4 o[4];
#pragma unroll
    for (int nt = 0; nt < 4; ++nt) o[nt] = (f32x4){0.f, 0.f, 0.f, 0.f};
    float mrow[4], lrow[4];
#pragma unroll
    for (int i = 0; i < 4; ++i) { mrow[i] = -__builtin_inff(); lrow[i] = 0.f; }

    // S = Q K^T for one tile (8 MFMA), into s[4]
    auto qkt = [&](f32x4* s, const u16* ks) {
#pragma unroll
      for (int nt = 0; nt < 4; ++nt) s[nt] = (f32x4){0.f, 0.f, 0.f, 0.f};
#pragma unroll
      for (int nt = 0; nt < 4; ++nt) {
        const int rb = nt * 16 + l16;
        ushx8 b0 = *(const ushx8*)(ks + rb * 64 + (quad ^ (rb & 7)) * 8);
        ushx8 b1 = *(const ushx8*)(ks + rb * 64 + ((quad + 4) ^ (rb & 7)) * 8);
        s[nt] = mfma_bf16(qf[0], b0, s[nt]);
        s[nt] = mfma_bf16(qf[1], b1, s[nt]);
      }
    };

    // online softmax + P store/load + PV for one tile
    auto smpv = [&](f32x4* s, int tt, const u16* vs) {
      const int kv0 = tt * 64;
      if (tt == tdiag) {
#pragma unroll
        for (int i = 0; i < 4; ++i) {
          const int qr = q0w + quad * 4 + i;
          float vv[4];
          float rmax = -__builtin_inff();
#pragma unroll
          for (int nt = 0; nt < 4; ++nt) {
            float v = s[nt][i];
            if ((kv0 + nt * 16 + l16) > qr) v = -__builtin_inff();
            vv[nt] = v;
            rmax = fmaxf(rmax, v);
          }
          rmax = red16max(rmax);
          const float mnew = fmaxf(mrow[i], rmax);
          const float al = __builtin_amdgcn_exp2f(mrow[i] - mnew);
          mrow[i] = mnew;
          float rsum = 0.f;
#pragma unroll
          for (int nt = 0; nt < 4; ++nt) {
            float p = __builtin_amdgcn_exp2f(vv[nt] - mnew);
            rsum += p;
            pswv[(quad * 4 + i) * 72 + nt * 16 + l16] = f2bf_rna(p);
          }
          lrow[i] = lrow[i] * al + rsum;
#pragma unroll
          for (int nt = 0; nt < 4; ++nt) o[nt][i] *= al;
        }
      } else {
#pragma unroll
        for (int i = 0; i < 4; ++i) {
          float rmax = fmaxf(fmaxf(s[0][i], s[1][i]), fmaxf(s[2][i], s[3][i]));
          rmax = red16max(rmax);
          const float mnew = fmaxf(mrow[i], rmax);
          const float al = __builtin_amdgcn_exp2f(mrow[i] - mnew);
          mrow[i] = mnew;
          float rsum = 0.f;
#pragma unroll
          for (int nt = 0; nt < 4; ++nt) {
            float p = __builtin_amdgcn_exp2f(s[nt][i] - mnew);
            rsum += p;
            pswv[(quad * 4 + i) * 72 + nt * 16 + l16] = f2bf_rna(p);
          }
          lrow[i] = lrow[i] * al + rsum;
#pragma unroll
          for (int nt = 0; nt < 4; ++nt) o[nt][i] *= al;
        }
      }
      // P A-fragments from wave-local LDS (DS in-order per wave)
      ushx8 pf0, pf1;
      {
        const u16* pp = pswv + l16 * 72 + quad * 8;
        pf0 = *(const ushx8*)pp;
        pf1 = *(const ushx8*)(pp + 32);
      }
      // O += P V
#pragma unroll
      for (int nt = 0; nt < 4; ++nt) {
        const int rb = nt * 16 + l16;
        ushx8 v0 = *(const ushx8*)(vs + rb * 64 + (quad ^ (rb & 7)) * 8);
        ushx8 v1 = *(const ushx8*)(vs + rb * 64 + ((quad + 4) ^ (rb & 7)) * 8);
        o[nt] = mfma_bf16(pf0, v0, o[nt]);
        o[nt] = mfma_bf16(pf1, v1, o[nt]);
      }
    };

    __syncthreads();  // previous phase's readers done before restaging slots
    stageKV(0, 0);
    stageKV(1, 1);

#pragma unroll 1
    for (int t = 0; t < ntiles; t += 2) {
      const int s0 = t % 3;
      const int s1 = (t + 1) % 3;
      __syncthreads();  // drains DMA for tiles t, t+1; readers of slot (t+2)%3 done

      if (t + 2 < ntiles) stageKV((t + 2) % 3, t + 2);

      const bool a1 = (t <= tdiag);          // wave-uniform
      const bool a2 = (t + 1 <= tdiag);

      f32x4 sA[4], sB[4];
      if (a1) qkt(sA, Ks[s0]);
      if (a2) qkt(sB, Ks[s1]);               // hoisted: overlaps softmax(t) below
      if (a1) smpv(sA, t, Vts[s0]);

      __syncthreads();  // readers of slot t%3 (QK/PV of t) done
      if (t + 3 < ntiles) stageKV((t + 3) % 3, t + 3);

      if (a2) smpv(sB, t + 1, Vts[s1]);
    }

    // O/l (16-lane l reduction deferred to here), write y_attn bf16
#pragma unroll
    for (int i = 0; i < 4; ++i) {
      const float inv = 1.f / red16sum(lrow[i]);
      const int trow = q0w + quad * 4 + i;
      u16* op = out + ((size_t)(b * Tn + trow)) * Cn + h * Dn + l16;
#pragma unroll
      for (int nt = 0; nt < 4; ++nt) op[nt * 16] = f2bf(o[nt][i] * inv);
    }
  }
}

// ---------------- launch ----------------
extern "C" void kernel_launch(void* const* d_in, const int* in_sizes, int n_in,
                              void* d_out, int out_size, void* d_ws, size_t ws_size,
                              hipStream_t stream) {
  const float* x = (const float*)d_in[0];
  const float* w_qkv = (const float*)d_in[1];
  const float* w_proj = (const float*)d_in[2];
  const float* b_proj = (const float*)d_in[3];
  float* out = (float*)d_out;
  char* ws = (char*)d_ws;

  u16* xb     = (u16*)(ws);                 // 16 MiB @ 0
  u16* wqkvb  = (u16*)(ws + 16777216);      //  6 MiB @ 16
  u16* wprojb = (u16*)(ws + 23068672);      //  2 MiB @ 22
  u16* qkb    = (u16*)(ws + 25165824);      // 32 MiB @ 24  (packed QK, stride 2048)
  u16* vtb    = (u16*)(ws + 58720256);      // 16 MiB @ 56
  u16* yb     = (u16*)(ws + 75497472);      // 16 MiB @ 72  (ends 88 MiB)

  cast3_kernel<<<12288, 256, 0, stream>>>(x, xb, 2097152,
                                          w_qkv, wqkvb, 786432,
                                          w_proj, wprojb, 262144);

  // QKV: 32 m-tiles x 24 n-tiles = 768 blocks (512 thr, 2 blocks/CU)
  gemm_qkv_k<<<768, 512, 0, stream>>>(xb, wqkvb, qkb, vtb);

  attn_kernel<<<dim3(4, Hn, Bn), 512, 0, stream>>>(qkb, vtb, yb);

  // proj: 64 m-tiles x 8 n-tiles = 512 blocks (256 thr, 2 blocks/CU)
  gemm_proj_k<<<512, 256, 0, stream>>>(yb, wprojb, out, b_proj);
}